// Round 19
// baseline (882.474 us; speedup 1.0000x reference)
//
#include <hip/hip_runtime.h>
#include <cstdint>
#include <cstddef>

#define NN 8000
#define NE 128000
#define NDv 40
#define EDv 10

typedef __attribute__((ext_vector_type(8))) short short8v;
typedef __attribute__((ext_vector_type(4))) float f32x4;

__device__ __forceinline__ float rcp_fast(float x) { return __builtin_amdgcn_rcpf(x); }
__device__ __forceinline__ float sigm(float x) { return rcp_fast(1.f + __expf(-x)); }
__device__ __forceinline__ float ftanh(float x) {
    float e = __expf(2.f * x);
    return 1.f - 2.f * rcp_fast(e + 1.f);
}
__device__ __forceinline__ short f2bf(float x) {   // RNE f32 -> bf16
    unsigned u = __builtin_bit_cast(unsigned, x);
    u += 0x7fffu + ((u >> 16) & 1u);
    return (short)(u >> 16);
}
__device__ __forceinline__ float wsum(float v) {
    for (int o = 32; o; o >>= 1) v += __shfl_down(v, o);
    return v;
}
__device__ __forceinline__ float wmax(float v) {
    for (int o = 32; o; o >>= 1) v = fmaxf(v, __shfl_down(v, o));
    return v;
}

// ---------------- CSR build (paired u/v via blockIdx.y) ----------------

__global__ __launch_bounds__(256) void csr_deg2_kernel(const int* __restrict__ ei_u, const int* __restrict__ ei_v,
                                                       int* __restrict__ deg_u, int* __restrict__ deg_v) {
    const int* ei = blockIdx.y ? ei_v : ei_u;
    int* deg = blockIdx.y ? deg_v : deg_u;
    int e = blockIdx.x * 256 + threadIdx.x;
    if (e < NE) atomicAdd(&deg[ei[e]], 1);
}

__global__ __launch_bounds__(256) void sef2_kernel(const int* __restrict__ ei_u, const int* __restrict__ ei_v,
                                                   const float* __restrict__ ef_u, const float* __restrict__ ef_v,
                                                   float* __restrict__ sef_u, float* __restrict__ sef_v) {
    const int* ei = blockIdx.y ? ei_v : ei_u;
    const float* ef = blockIdx.y ? ef_v : ef_u;
    float* sef = blockIdx.y ? sef_v : sef_u;
    int t = blockIdx.x * 256 + threadIdx.x;   // exactly NE*EDv
    int e = t / EDv, k = t % EDv;
    atomicAdd(&sef[ei[e] * EDv + k], ef[t]);
}

__global__ __launch_bounds__(64) void csr_scan2_kernel(const int* __restrict__ deg_u, const int* __restrict__ deg_v,
                                                       int* __restrict__ off_u, int* __restrict__ off_v,
                                                       int* __restrict__ woff_u, int* __restrict__ woff_v) {
    const int* deg = blockIdx.x ? deg_v : deg_u;
    int* off = blockIdx.x ? off_v : off_u;
    int* woff = blockIdx.x ? woff_v : woff_u;
    int l = threadIdx.x;
    int base = l * 125;
    int s = 0;
    for (int i = 0; i < 125; ++i) s += deg[base + i];
    int pre = s;
    for (int o = 1; o < 64; o <<= 1) { int t = __shfl_up(pre, o); if (l >= o) pre += t; }
    pre -= s;   // exclusive prefix
    int run = pre;
    for (int i = 0; i < 125; ++i) {
        off[base + i] = run; woff[base + i] = run;
        run += deg[base + i];
    }
    if (l == 63) off[NN] = run;
}

__global__ __launch_bounds__(256) void csr_fill2_kernel(const int* __restrict__ ei_u, const int* __restrict__ ei_v,
                                                        int* __restrict__ woff_u, int* __restrict__ woff_v,
                                                        int* __restrict__ dl_u, int* __restrict__ dl_v) {
    const int* ei = blockIdx.y ? ei_v : ei_u;
    int* woff = blockIdx.y ? woff_v : woff_u;
    int* dlist = blockIdx.y ? dl_v : dl_u;
    int e = blockIdx.x * 256 + threadIdx.x;
    if (e < NE) { int p = atomicAdd(&woff[ei[e]], 1); dlist[p] = ei[NE + e]; }
}

// ---------------- message passing ----------------

__global__ __launch_bounds__(256) void node_proj2_kernel(const float* __restrict__ h_u, const float* __restrict__ h_v,
                                                         const float* __restrict__ Uw_u, const float* __restrict__ Uw_v,
                                                         float* __restrict__ A_u, float* __restrict__ B_u,
                                                         float* __restrict__ A_v, float* __restrict__ B_v) {
    const float* h = blockIdx.y ? h_v : h_u;
    const float* Uw = blockIdx.y ? Uw_v : Uw_u;
    float* A = blockIdx.y ? A_v : A_u;
    float* B = blockIdx.y ? B_v : B_u;
    __shared__ float W[40][81];
    int tid = threadIdx.x;
    for (int s = tid; s < 3200; s += 256) W[s / 80][s % 80] = Uw[(s / 80) * 90 + (s % 80)];
    __syncthreads();
    int t = blockIdx.x * 256 + tid;   // exactly 8000*40
    int n = t / NDv, i = t % NDv;
    float hreg[40];
    const float* hr = h + n * NDv;
#pragma unroll
    for (int k4 = 0; k4 < 10; ++k4) {
        float4 v = *reinterpret_cast<const float4*>(hr + k4 * 4);
        hreg[k4 * 4 + 0] = v.x; hreg[k4 * 4 + 1] = v.y; hreg[k4 * 4 + 2] = v.z; hreg[k4 * 4 + 3] = v.w;
    }
    float a = 0.f, b = 0.f;
#pragma unroll
    for (int k = 0; k < NDv; ++k) { a += W[i][k] * hreg[k]; b += W[i][40 + k] * hreg[k]; }
    A[t] = a; B[t] = b;
}

// one full MP round: gather(msg in LDS) -> update(hout) -> proj for next round (A/B out).
// block = 320 threads = 8 nodes x 40 features (R17-proven); paired u/v via blockIdx.y.
__global__ __launch_bounds__(320) void mp_round2_kernel(
    const int* __restrict__ off_u, const int* __restrict__ dl_u, const float* __restrict__ sef_u,
    const float* __restrict__ UwE_u, const float* __restrict__ Ub_u,
    const float* __restrict__ Mw_u, const float* __restrict__ Mb_u, const float* __restrict__ UwN_u,
    const float* __restrict__ h_u, const float* __restrict__ A_u, const float* __restrict__ B_u,
    float* __restrict__ hout_u, float* __restrict__ Ao_u, float* __restrict__ Bo_u,
    const int* __restrict__ off_v, const int* __restrict__ dl_v, const float* __restrict__ sef_v,
    const float* __restrict__ UwE_v, const float* __restrict__ Ub_v,
    const float* __restrict__ Mw_v, const float* __restrict__ Mb_v, const float* __restrict__ UwN_v,
    const float* __restrict__ h_v, const float* __restrict__ A_v, const float* __restrict__ B_v,
    float* __restrict__ hout_v, float* __restrict__ Ao_v, float* __restrict__ Bo_v,
    int has_next) {
    const int* off = blockIdx.y ? off_v : off_u;
    const int* dlist = blockIdx.y ? dl_v : dl_u;
    const float* sef = blockIdx.y ? sef_v : sef_u;
    const float* UwE = blockIdx.y ? UwE_v : UwE_u;
    const float* Ub = blockIdx.y ? Ub_v : Ub_u;
    const float* Mw = blockIdx.y ? Mw_v : Mw_u;
    const float* Mb = blockIdx.y ? Mb_v : Mb_u;
    const float* UwN = blockIdx.y ? UwN_v : UwN_u;
    const float* h = blockIdx.y ? h_v : h_u;
    const float* A = blockIdx.y ? A_v : A_u;
    const float* B = blockIdx.y ? B_v : B_u;
    float* hout = blockIdx.y ? hout_v : hout_u;
    float* Ao = blockIdx.y ? Ao_v : Ao_u;
    float* Bo = blockIdx.y ? Bo_v : Bo_u;

    __shared__ float WM[40][81];
    __shared__ float WU[40][81];
    __shared__ float msgS[8][40];
    __shared__ float hS[8][41];
    __shared__ float houtS[8][41];

    int tid = threadIdx.x;
    for (int s = tid; s < 3200; s += 320) WM[s / 80][s % 80] = Mw[s];
    if (has_next)
        for (int s = tid; s < 3200; s += 320) WU[s / 80][s % 80] = UwN[(s / 80) * 90 + (s % 80)];
    int ln = tid / NDv, i = tid % NDv;
    int n = blockIdx.x * 8 + ln;
    int t = n * NDv + i;
    hS[ln][i] = h[t];

    const float* we = UwE + i * 90 + 80;
    const float* se = sef + n * EDv;
    int p0 = off[n], p1 = off[n + 1];
    float acc = (float)(p1 - p0) * (A[t] + Ub[i]);
#pragma unroll
    for (int k = 0; k < EDv; ++k) acc += we[k] * se[k];
    for (int p = p0; p < p1; ++p) acc += B[dlist[p] * NDv + i];
    msgS[ln][i] = acc;
    __syncthreads();

    float a2 = Mb[i];
#pragma unroll
    for (int k = 0; k < NDv; ++k) a2 += WM[i][k] * hS[ln][k];
#pragma unroll
    for (int k = 0; k < NDv; ++k) a2 += WM[i][40 + k] * msgS[ln][k];
    float ho = fmaxf(a2, 0.f);
    hout[t] = ho;
    if (has_next) {
        houtS[ln][i] = ho;
        __syncthreads();
        float a = 0.f, b = 0.f;
#pragma unroll
        for (int k = 0; k < NDv; ++k) { float hv = houtS[ln][k]; a += WU[i][k] * hv; b += WU[i][40 + k] * hv; }
        Ao[t] = a; Bo[t] = b;
    }
}

// ---------------- set2set pair (algebraically collapsed; zero initial state) ----------------

__global__ __launch_bounds__(64) void s2s_init2_kernel(const float* __restrict__ bih_u, const float* __restrict__ bhh_u,
                                                       const float* __restrict__ bih_v, const float* __restrict__ bhh_v,
                                                       float* __restrict__ h1_u, float* __restrict__ c1_u,
                                                       float* __restrict__ h1_v, float* __restrict__ c1_v) {
    const float* bih = blockIdx.y ? bih_v : bih_u;
    const float* bhh = blockIdx.y ? bhh_v : bhh_u;
    float* h1 = blockIdx.y ? h1_v : h1_u;
    float* c1 = blockIdx.y ? c1_v : c1_u;
    int i = threadIdx.x;
    if (i < 40) {
        float gi = bih[i] + bhh[i];
        float gg = bih[80 + i] + bhh[80 + i];
        float go = bih[120 + i] + bhh[120 + i];
        float c = sigm(gi) * ftanh(gg);
        c1[i] = c;
        h1[i] = sigm(go) * ftanh(c);
    }
}

// per-node step 0: e=dot(h0/ht, h1); 2-way softmax; q=[h1, r]; also rT[i][n] for coalesced gates1
__global__ __launch_bounds__(256) void s2s_step0_kernel(const float* __restrict__ h0_u, const float* __restrict__ ht_u,
                                                        const float* __restrict__ h1_u, float* __restrict__ q_u,
                                                        float* __restrict__ rT_u,
                                                        const float* __restrict__ h0_v, const float* __restrict__ ht_v,
                                                        const float* __restrict__ h1_v, float* __restrict__ q_v,
                                                        float* __restrict__ rT_v) {
    const float* h0 = blockIdx.y ? h0_v : h0_u;
    const float* ht = blockIdx.y ? ht_v : ht_u;
    const float* h1 = blockIdx.y ? h1_v : h1_u;
    float* q = blockIdx.y ? q_v : q_u;
    float* rT = blockIdx.y ? rT_v : rT_u;
    int tid = threadIdx.x;
    int nl = tid >> 2, lg = tid & 3;
    int n = blockIdx.x * 64 + nl;
    float h0r[10], htr[10];
    float e0 = 0.f, e1 = 0.f;
#pragma unroll
    for (int k = 0; k < 10; ++k) {
        int i = lg * 10 + k;
        h0r[k] = h0[n * 40 + i];
        htr[k] = ht[n * 40 + i];
        float hv = h1[i];
        e0 += h0r[k] * hv;
        e1 += htr[k] * hv;
    }
    e0 += __shfl_xor(e0, 1); e0 += __shfl_xor(e0, 2);
    e1 += __shfl_xor(e1, 1); e1 += __shfl_xor(e1, 2);
    float m = fmaxf(e0, e1);
    float p0 = __expf(e0 - m), p1 = __expf(e1 - m);
    float inv = rcp_fast(p0 + p1);
    float a0 = p0 * inv, a1 = p1 * inv;
#pragma unroll
    for (int k = 0; k < 10; ++k) {
        int i = lg * 10 + k;
        float r = a0 * h0r[k] + a1 * htr[k];
        q[n * 80 + i] = h1[i];
        q[n * 80 + 40 + i] = r;
        rT[i * NN + n] = r;
    }
}

__global__ __launch_bounds__(64) void s2s_base2_kernel(const float* __restrict__ Wih_u, const float* __restrict__ Whh_u,
                                                       const float* __restrict__ bih_u, const float* __restrict__ bhh_u,
                                                       const float* __restrict__ h1_u,
                                                       const float* __restrict__ Wih_v, const float* __restrict__ Whh_v,
                                                       const float* __restrict__ bih_v, const float* __restrict__ bhh_v,
                                                       const float* __restrict__ h1_v,
                                                       float* __restrict__ base2) {
    const float* Wih = blockIdx.y ? Wih_v : Wih_u;
    const float* Whh = blockIdx.y ? Whh_v : Whh_u;
    const float* bih = blockIdx.y ? bih_v : bih_u;
    const float* bhh = blockIdx.y ? bhh_v : bhh_u;
    const float* h1 = blockIdx.y ? h1_v : h1_u;
    int j = blockIdx.x;
    int lane = threadIdx.x;
    float p = 0.f;
    if (lane < 40) p = (Wih[j * 80 + lane] + Whh[j * 40 + lane]) * h1[lane];
    p = wsum(p);
    if (lane == 0) base2[blockIdx.y * 160 + j] = p + bih[j] + bhh[j];
}

// step-1 gates: gT[j][n] = base[j] + Wih[j,40:80]·r[n]; r read coalesced from rT
__global__ __launch_bounds__(256) void s2s_gates1_kernel(const float* __restrict__ rT_u, const float* __restrict__ Wih_u,
                                                         float* __restrict__ gT_u,
                                                         const float* __restrict__ rT_v, const float* __restrict__ Wih_v,
                                                         float* __restrict__ gT_v,
                                                         const float* __restrict__ base2) {
    const float* rT = blockIdx.y ? rT_v : rT_u;
    const float* Wih = blockIdx.y ? Wih_v : Wih_u;
    float* gatesT = blockIdx.y ? gT_v : gT_u;
    const float* base = base2 + blockIdx.y * 160;
    int t = blockIdx.x * 256 + threadIdx.x;   // exactly 8000*20
    int n = t % NN;
    int jg = t / NN;
    float rr[40];
#pragma unroll
    for (int k = 0; k < 40; ++k) rr[k] = rT[k * NN + n];
#pragma unroll
    for (int jj = 0; jj < 8; ++jj) {
        int j = jg * 8 + jj;
        const float* wi = Wih + j * 80 + 40;
        float acc = base[j];
#pragma unroll
        for (int k = 0; k < 40; ++k) acc += wi[k] * rr[k];
        gatesT[j * NN + n] = acc;
    }
}

__global__ __launch_bounds__(256) void s2s_upd1_kernel(const float* __restrict__ gT_u, const float* __restrict__ h0_u,
                                                       const float* __restrict__ ht_u, const float* __restrict__ c1_u,
                                                       float* __restrict__ q_u,
                                                       const float* __restrict__ gT_v, const float* __restrict__ h0_v,
                                                       const float* __restrict__ ht_v, const float* __restrict__ c1_v,
                                                       float* __restrict__ q_v) {
    const float* gT = blockIdx.y ? gT_v : gT_u;
    const float* h0 = blockIdx.y ? h0_v : h0_u;
    const float* ht = blockIdx.y ? ht_v : ht_u;
    const float* c1 = blockIdx.y ? c1_v : c1_u;
    float* q = blockIdx.y ? q_v : q_u;
    int tid = threadIdx.x;
    int nl = tid >> 2, lg = tid & 3;
    int n = blockIdx.x * 64 + nl;
    float h0r[10], htr[10], hnr[10];
    float e0 = 0.f, e1 = 0.f;
#pragma unroll
    for (int k = 0; k < 10; ++k) {
        int i = lg * 10 + k;
        float gi = gT[i * NN + n];
        float gf = gT[(40 + i) * NN + n];
        float gg = gT[(80 + i) * NN + n];
        float go = gT[(120 + i) * NN + n];
        float cn = sigm(gf) * c1[i] + sigm(gi) * ftanh(gg);
        float hn = sigm(go) * ftanh(cn);
        hnr[k] = hn;
        h0r[k] = h0[n * 40 + i];
        htr[k] = ht[n * 40 + i];
        e0 += h0r[k] * hn;
        e1 += htr[k] * hn;
    }
    e0 += __shfl_xor(e0, 1); e0 += __shfl_xor(e0, 2);
    e1 += __shfl_xor(e1, 1); e1 += __shfl_xor(e1, 2);
    float m = fmaxf(e0, e1);
    float p0 = __expf(e0 - m), p1 = __expf(e1 - m);
    float inv = rcp_fast(p0 + p1);
    float a0 = p0 * inv, a1 = p1 * inv;
#pragma unroll
    for (int k = 0; k < 10; ++k) {
        int i = lg * 10 + k;
        q[n * 80 + i] = hnr[k];
        q[n * 80 + 40 + i] = a0 * h0r[k] + a1 * htr[k];
    }
}

// ---------------- bf16 casts + f32 transposed copy (u/v via blockIdx.y) ----------------

__global__ __launch_bounds__(256) void cast_all_kernel(const float* __restrict__ gu, const float* __restrict__ gv,
                                                       short* __restrict__ ouT, short* __restrict__ ovT,
                                                       short* __restrict__ oub, short* __restrict__ ovb,
                                                       float* __restrict__ qTu, float* __restrict__ qTv) {
    const float* g = blockIdx.y ? gv : gu;
    if (blockIdx.x < 2500) {   // transposed [80][8000]: bf16 + f32 copies
        short* o = blockIdx.y ? ovT : ouT;
        float* qT = blockIdx.y ? qTv : qTu;
        int t = blockIdx.x * 256 + threadIdx.x;
        int m = t % NN, f = t / NN;
        float val = g[m * 80 + f];
        o[t] = f2bf(val);
        qT[t] = val;
    } else {                    // padded row-major [8000][96]
        short* o = blockIdx.y ? ovb : oub;
        int t = (blockIdx.x - 2500) * 256 + threadIdx.x;
        int m = t / 96, k = t % 96;
        o[t] = (k < 80) ? f2bf(g[m * 80 + k]) : (short)0;
    }
}

// ---------------- fused interaction + after-feature (barrier-free, SW-pipelined) ----------------
// y-split 4 + __launch_bounds__(256,4): 4 blocks/CU resident (16 waves/CU) to hide latency.

__global__ __launch_bounds__(256, 4) void fused_kernel(const short* __restrict__ gub, const short* __restrict__ gvb,
                                                       const short* __restrict__ guT, const short* __restrict__ gvT,
                                                       float* __restrict__ inter,
                                                       float* __restrict__ uafT, float* __restrict__ vafT) {
    __shared__ short P[4][16][72];   // per-wave [row][col], 144B row stride
    const short* Xb; const short* Yb; const short* YT; float* afT;
    bool storeI = (blockIdx.z == 0);
    if (storeI) { Xb = gub; Yb = gvb; YT = gvT; afT = uafT; }
    else        { Xb = gvb; Yb = gub; YT = guT; afT = vafT; }
    int tid = threadIdx.x;
    int w = tid >> 6, l = tid & 63;
    int lrow = l & 15, lk = l >> 4;
    int x0 = blockIdx.x * 64;
    int it0 = (125 * blockIdx.y) >> 2;
    int it1 = (125 * (blockIdx.y + 1)) >> 2;
    short8v a_x[3];
    const short* arow = Xb + (size_t)(x0 + w * 16 + lrow) * 96 + lk * 8;
#pragma unroll
    for (int ks = 0; ks < 3; ++ks) a_x[ks] = *reinterpret_cast<const short8v*>(arow + ks * 32);
    const short* ybase = Yb + (size_t)lrow * 96 + lk * 8;

    f32x4 acc[5] = {};
    short8v bc[12], bn[12];
#pragma unroll
    for (int i = 0; i < 12; ++i) {
        int ks = i >> 2, nt = i & 3;
        bc[i] = *reinterpret_cast<const short8v*>(ybase + (size_t)(it0 * 64 + nt * 16) * 96 + ks * 32);
    }
    for (int it = it0; it < it1; ++it) {
        int k0 = it * 64;
        if (it + 1 < it1) {
#pragma unroll
            for (int i = 0; i < 12; ++i) {
                int ks = i >> 2, nt = i & 3;
                bn[i] = *reinterpret_cast<const short8v*>(ybase + (size_t)(k0 + 64 + nt * 16) * 96 + ks * 32);
            }
        }
        short8v byt[10];
#pragma unroll
        for (int ks2 = 0; ks2 < 2; ++ks2)
#pragma unroll
            for (int ft = 0; ft < 5; ++ft)
                byt[ks2 * 5 + ft] = *reinterpret_cast<const short8v*>(YT + (size_t)(ft * 16 + lrow) * NN + k0 + ks2 * 32 + lk * 8);
        f32x4 accI[4] = {};
#pragma unroll
        for (int ks = 0; ks < 3; ++ks)
#pragma unroll
            for (int nt = 0; nt < 4; ++nt)
                accI[nt] = __builtin_amdgcn_mfma_f32_16x16x32_bf16(a_x[ks], bc[ks * 4 + nt], accI[nt], 0, 0, 0);
#pragma unroll
        for (int nt = 0; nt < 4; ++nt)
#pragma unroll
            for (int r = 0; r < 4; ++r)
                P[w][lk * 4 + r][nt * 16 + lrow] = f2bf(ftanh(accI[nt][r]));
        // wave-private LDS: same-wave write->read is in-order, no barrier needed
#pragma unroll
        for (int ks2 = 0; ks2 < 2; ++ks2) {
            short8v ap = *reinterpret_cast<const short8v*>(&P[w][lrow][ks2 * 32 + lk * 8]);
#pragma unroll
            for (int ft = 0; ft < 5; ++ft)
                acc[ft] = __builtin_amdgcn_mfma_f32_16x16x32_bf16(ap, byt[ks2 * 5 + ft], acc[ft], 0, 0, 0);
        }
        if (storeI) {
#pragma unroll
            for (int nt = 0; nt < 4; ++nt)
#pragma unroll
                for (int r = 0; r < 4; ++r)
                    inter[(size_t)(x0 + w * 16 + lk * 4 + r) * NN + (k0 + nt * 16 + lrow)] = accI[nt][r];
        }
#pragma unroll
        for (int i = 0; i < 12; ++i) bc[i] = bn[i];
    }
    int xout = x0 + w * 16 + lk * 4;
#pragma unroll
    for (int ft = 0; ft < 5; ++ft)
#pragma unroll
        for (int r = 0; r < 4; ++r)
            atomicAdd(&afT[(size_t)(ft * 16 + lrow) * NN + xout + r], acc[ft][r]);
}

// ---------------- set2set pool (batch 1, h_d=160; paired u/v; step-0 collapsed) ----------------

__global__ __launch_bounds__(256) void pool_init2_kernel(const float* __restrict__ bih_u, const float* __restrict__ bhh_u,
                                                         const float* __restrict__ bih_v, const float* __restrict__ bhh_v,
                                                         float* __restrict__ ph_u, float* __restrict__ pc_u,
                                                         float* __restrict__ pq_u,
                                                         float* __restrict__ ph_v, float* __restrict__ pc_v,
                                                         float* __restrict__ pq_v) {
    const float* bih = blockIdx.y ? bih_v : bih_u;
    const float* bhh = blockIdx.y ? bhh_v : bhh_u;
    float* ph = blockIdx.y ? ph_v : ph_u;
    float* pc = blockIdx.y ? pc_v : pc_u;
    float* pq = blockIdx.y ? pq_v : pq_u;
    int i = threadIdx.x;
    if (i < 160) {
        float gi = bih[i] + bhh[i];
        float gg = bih[320 + i] + bhh[320 + i];
        float go = bih[480 + i] + bhh[480 + i];
        float c = sigm(gi) * ftanh(gg);
        pc[i] = c;
        float h = sigm(go) * ftanh(c);
        ph[i] = h;
        pq[i] = h;
    }
}

__global__ __launch_bounds__(64) void gates_pool2_kernel(const float* __restrict__ Wih_u, const float* __restrict__ Whh_u,
                                                         const float* __restrict__ bih_u, const float* __restrict__ bhh_u,
                                                         const float* __restrict__ q_u, const float* __restrict__ h_u,
                                                         const float* __restrict__ Wih_v, const float* __restrict__ Whh_v,
                                                         const float* __restrict__ bih_v, const float* __restrict__ bhh_v,
                                                         const float* __restrict__ q_v, const float* __restrict__ h_v,
                                                         float* __restrict__ gts2) {
    const float* Wih = blockIdx.y ? Wih_v : Wih_u;
    const float* Whh = blockIdx.y ? Whh_v : Whh_u;
    const float* bih = blockIdx.y ? bih_v : bih_u;
    const float* bhh = blockIdx.y ? bhh_v : bhh_u;
    const float* q = blockIdx.y ? q_v : q_u;
    const float* h = blockIdx.y ? h_v : h_u;
    float* gts = gts2 + blockIdx.y * 640;
    int j = blockIdx.x;
    int lane = threadIdx.x;
    const float* wi = Wih + j * 320;
    const float* wh = Whh + j * 160;
    float p = 0.f;
#pragma unroll
    for (int k4 = 0; k4 < 5; ++k4) { int k = lane + k4 * 64; p += wi[k] * q[k]; }
#pragma unroll
    for (int k4 = 0; k4 < 3; ++k4) { int k = lane + k4 * 64; if (k < 160) p += wh[k] * h[k]; }
    p = wsum(p);
    if (lane == 0) gts[j] = p + bih[j] + bhh[j];
}

__global__ __launch_bounds__(256) void pool_point2_kernel(const float* __restrict__ gts2,
                                                          float* __restrict__ h_u, float* __restrict__ c_u,
                                                          float* __restrict__ q_u,
                                                          float* __restrict__ h_v, float* __restrict__ c_v,
                                                          float* __restrict__ q_v) {
    const float* gts = gts2 + blockIdx.y * 640;
    float* h = blockIdx.y ? h_v : h_u;
    float* c = blockIdx.y ? c_v : c_u;
    float* q = blockIdx.y ? q_v : q_u;
    int tid = threadIdx.x;
    if (tid < 160) {
        float cn = sigm(gts[160 + tid]) * c[tid] + sigm(gts[tid]) * ftanh(gts[320 + tid]);
        c[tid] = cn;
        float hn = sigm(gts[480 + tid]) * ftanh(cn);
        h[tid] = hn;
        q[tid] = hn;   // q_star[0:160] = h
    }
}

__global__ __launch_bounds__(256) void pool_scores2_kernel(const float* __restrict__ uafT, const float* __restrict__ qTu,
                                                           const float* __restrict__ h_u, float* __restrict__ sc_u,
                                                           const float* __restrict__ vafT, const float* __restrict__ qTv,
                                                           const float* __restrict__ h_v, float* __restrict__ sc_v,
                                                           float* __restrict__ pmax2) {
    const float* afT = blockIdx.y ? vafT : uafT;
    const float* qT = blockIdx.y ? qTv : qTu;
    const float* h = blockIdx.y ? h_v : h_u;
    float* scores = blockIdx.y ? sc_v : sc_u;
    float* pmax = pmax2 + blockIdx.y * 32;
    int tid = threadIdx.x;
    int n = blockIdx.x * 256 + tid;
    float s = -3.4e38f;
    if (n < NN) {
        float acc = 0.f;
#pragma unroll 8
        for (int k = 0; k < 80; ++k) acc += afT[k * NN + n] * h[k];
#pragma unroll 8
        for (int k = 0; k < 80; ++k) acc += qT[k * NN + n] * h[80 + k];
        scores[n] = acc;
        s = acc;
    }
    __shared__ float red[4];
    float m = wmax(s);
    if ((tid & 63) == 0) red[tid >> 6] = m;
    __syncthreads();
    if (tid == 0) pmax[blockIdx.x] = fmaxf(fmaxf(red[0], red[1]), fmaxf(red[2], red[3]));
}

__global__ __launch_bounds__(256) void pool_r2_kernel(const float* __restrict__ uafT, const float* __restrict__ qTu,
                                                      const float* __restrict__ sc_u,
                                                      const float* __restrict__ vafT, const float* __restrict__ qTv,
                                                      const float* __restrict__ sc_v,
                                                      const float* __restrict__ pmax2,
                                                      float* __restrict__ pq_u, float* __restrict__ pq_v) {
    const float* afT = blockIdx.y ? vafT : uafT;
    const float* qT = blockIdx.y ? qTv : qTu;
    const float* scores = blockIdx.y ? sc_v : sc_u;
    float* q = blockIdx.y ? pq_v : pq_u;
    const float* pmax = pmax2 + blockIdx.y * 32;
    int f = blockIdx.x;   // 0..159
    int tid = threadIdx.x;
    __shared__ float smax;
    __shared__ float reda[4], redd[4];
    if (tid < 64) {
        float m = (tid < 32) ? pmax[tid] : -3.4e38f;
        m = wmax(m);
        if (tid == 0) smax = m;
    }
    __syncthreads();
    float m = smax;
    const float* x = (f < 80) ? (afT + (size_t)f * NN) : (qT + (size_t)(f - 80) * NN);
    float acc = 0.f, den = 0.f;
    for (int n = tid; n < NN; n += 256) { float e = __expf(scores[n] - m); den += e; acc += e * x[n]; }
    float wa = wsum(acc), wd = wsum(den);
    if ((tid & 63) == 0) { reda[tid >> 6] = wa; redd[tid >> 6] = wd; }
    __syncthreads();
    if (tid == 0) {
        float A = reda[0] + reda[1] + reda[2] + reda[3];
        float D = redd[0] + redd[1] + redd[2] + redd[3];
        q[160 + f] = A * rcp_fast(D);
    }
}

// ---------------- final MLP ----------------

__global__ __launch_bounds__(64) void gemv_kernel(const float* __restrict__ W, const float* __restrict__ b,
                                                  const float* __restrict__ x, float* __restrict__ y,
                                                  int K, int relu) {
    int j = blockIdx.x;
    int lane = threadIdx.x;
    const float* w = W + (size_t)j * K;
    float p = 0.f;
    for (int k = lane; k < K; k += 64) p += w[k] * x[k];
    p = wsum(p);
    if (lane == 0) {
        p += b[j];
        y[j] = relu ? fmaxf(p, 0.f) : p;
    }
}

// ---------------- launch ----------------

extern "C" void kernel_launch(void* const* d_in, const int* in_sizes, int n_in,
                              void* d_out, int out_size, void* d_ws, size_t ws_size,
                              hipStream_t stream) {
    const float* nodes_u = (const float*)d_in[0];
    const int* ei_u = (const int*)d_in[1];
    const float* ef_u = (const float*)d_in[2];
    const float* nodes_v = (const float*)d_in[3];
    const int* ei_v = (const int*)d_in[4];
    const float* ef_v = (const float*)d_in[5];
    const float* Uw_u = (const float*)d_in[6];
    const float* Ub_u = (const float*)d_in[7];
    const float* Mw_u = (const float*)d_in[8];
    const float* Mb_u = (const float*)d_in[9];
    const float* Uw_v = (const float*)d_in[10];
    const float* Ub_v = (const float*)d_in[11];
    const float* Mw_v = (const float*)d_in[12];
    const float* Mb_v = (const float*)d_in[13];
    const float* lsWih = (const float*)d_in[14];
    const float* lsWhh = (const float*)d_in[15];
    const float* lsbih = (const float*)d_in[16];
    const float* lsbhh = (const float*)d_in[17];
    const float* lvWih = (const float*)d_in[18];
    const float* lvWhh = (const float*)d_in[19];
    const float* lvbih = (const float*)d_in[20];
    const float* lvbhh = (const float*)d_in[21];
    const float* gsWih = (const float*)d_in[22];
    const float* gsWhh = (const float*)d_in[23];
    const float* gsbih = (const float*)d_in[24];
    const float* gsbhh = (const float*)d_in[25];
    const float* gvWih = (const float*)d_in[26];
    const float* gvWhh = (const float*)d_in[27];
    const float* gvbih = (const float*)d_in[28];
    const float* gvbhh = (const float*)d_in[29];
    const float* w1 = (const float*)d_in[30];
    const float* b1 = (const float*)d_in[31];
    const float* w2 = (const float*)d_in[32];
    const float* b2 = (const float*)d_in[33];
    const float* w3 = (const float*)d_in[34];
    const float* b3 = (const float*)d_in[35];
    const float* w4 = (const float*)d_in[36];
    const float* b4 = (const float*)d_in[37];

    float* ws = (float*)d_ws;
    float* hA_u = ws + 0;
    float* hB_u = ws + 320000;
    float* hA_v = ws + 640000;
    float* hB_v = ws + 960000;
    float* A0_u = ws + 1600000;
    float* B0_u = ws + 1920000;
    float* q_u  = ws + 2240000;   // gu [8000,80]; during MP: A1_u/B1_u ping-pong
    float* q_v  = ws + 2880000;   // gv [8000,80]; during MP: A1_v/B1_v
    float* A1_u = ws + 2240000;
    float* B1_u = ws + 2560000;
    float* A1_v = ws + 2880000;
    float* B1_v = ws + 3200000;
    float* sef_u = ws + 4160000;  // [8000][10] — MP phase
    float* sef_v = ws + 4240000;  // [8000][10]
    float* gT_u = ws + 4160000;   // [160][8000] — s2s phase (sef dead after MP)
    float* gT_v = ws + 5440000;   // [160][8000] — overlaps uafT/vafT (memset later)
    float* uafT = ws + 5440000;   // [80][8000] — fused phase (gT_v dead)
    float* vafT = ws + 6080000;   // [80][8000]
    float* rT_u = ws + 1600000;   // [40][8000] — s2s phase (A0_u dead); overwritten by qT_u in cast
    float* rT_v = ws + 1920000;   // [40][8000] (B0_u region)
    float* qT_u = ws + 1600000;   // [80][8000] f32 — cast phase
    float* qT_v = ws + 2240000;   // [80][8000] f32 — q_u region dead after cast
    float* sc_u = ws + 6720000;   // [8000]
    float* sc_v = ws + 6728000;   // [8000]
    float* pmax2 = ws + 6736000;  // [2][32]
    float* pq_u = ws + 6736080;   // [320]  (pq_u|pq_v contiguous = MLP input)
    float* pq_v = ws + 6736400;   // [320]
    float* ph_u = ws + 6736720;   // [160]
    float* pc_u = ws + 6736880;   // [160]
    float* ph_v = ws + 6737040;   // [160]
    float* pc_v = ws + 6737200;   // [160]
    float* pgts2 = ws + 6737360;  // [2][640]
    float* mx1  = ws + 6738640;   // 360
    float* mx2  = ws + 6739000;   // 200
    float* mx3  = ws + 6739200;   // 120
    float* h1_u = ws + 6739320;   // [40]
    float* c1_u = ws + 6739360;   // [40]
    float* h1_v = ws + 6739400;   // [40]
    float* c1_v = ws + 6739440;   // [40]
    float* base2 = ws + 6739480;  // [2][160] -> ends 6739800
    int* ioff_u   = (int*)(ws + 6740000);   // 8064
    int* idlist_u = (int*)(ws + 6748064);   // 128000
    int* ioff_v   = (int*)(ws + 6876064);   // 8064
    int* idlist_v = (int*)(ws + 6884128);   // 128000
    int* iwoff_u  = (int*)(ws + 7012128);   // 8064 (CSR phase only)
    int* ideg_u   = (int*)(ws + 7020192);   // 8064
    int* iwoff_v  = (int*)(ws + 7028256);   // 8064
    int* ideg_v   = (int*)(ws + 7036320);   // 8064 -> ends 7044384
    // MP phase: v proj set 0 (CSR scratch above dead by MP)
    float* A0_v = ws + 7339536;   // [320000]
    float* B0_v = ws + 7659536;   // [320000] -> ends 7979536

    // bf16 buffers reuse the (dead by then) message-passing region
    short* guT = (short*)(ws + 0);        // [80][8000]
    short* gvT = (short*)(ws + 320000);   // [80][8000]
    short* gub = (short*)(ws + 640000);   // [8000][96]
    short* gvb = (short*)(ws + 1024000);  // [8000][96]

    float* out = (float*)d_out;
    float* inter = out + 1;

    // ---- CSR + edge-feature sums (paired) ----
    hipMemsetAsync(ideg_u, 0, (7044384 - 7020192) * sizeof(int), stream);  // ideg_u, iwoff_v, ideg_v
    hipMemsetAsync(sef_u, 0, 2 * NN * EDv * sizeof(float), stream);        // sef_u + sef_v
    csr_deg2_kernel<<<dim3(500, 2), 256, 0, stream>>>(ei_u, ei_v, ideg_u, ideg_v);
    csr_scan2_kernel<<<2, 64, 0, stream>>>(ideg_u, ideg_v, ioff_u, ioff_v, iwoff_u, iwoff_v);
    csr_fill2_kernel<<<dim3(500, 2), 256, 0, stream>>>(ei_u, ei_v, iwoff_u, iwoff_v, idlist_u, idlist_v);
    sef2_kernel<<<dim3(5000, 2), 256, 0, stream>>>(ei_u, ei_v, ef_u, ef_v, sef_u, sef_v);

    // ---- message passing: proj0 + 3 fused rounds (8 nodes/block, R17-proven) ----
    node_proj2_kernel<<<dim3(1250, 2), 256, 0, stream>>>(nodes_u, nodes_v, Uw_u, Uw_v, A0_u, B0_u, A0_v, B0_v);
    mp_round2_kernel<<<dim3(1000, 2), 320, 0, stream>>>(
        ioff_u, idlist_u, sef_u, Uw_u, Ub_u, Mw_u, Mb_u, Uw_u + 3600,
        nodes_u, A0_u, B0_u, hA_u, A1_u, B1_u,
        ioff_v, idlist_v, sef_v, Uw_v, Ub_v, Mw_v, Mb_v, Uw_v + 3600,
        nodes_v, A0_v, B0_v, hA_v, A1_v, B1_v, 1);
    mp_round2_kernel<<<dim3(1000, 2), 320, 0, stream>>>(
        ioff_u, idlist_u, sef_u, Uw_u + 3600, Ub_u + 40, Mw_u + 3200, Mb_u + 40, Uw_u + 7200,
        hA_u, A1_u, B1_u, hB_u, A0_u, B0_u,
        ioff_v, idlist_v, sef_v, Uw_v + 3600, Ub_v + 40, Mw_v + 3200, Mb_v + 40, Uw_v + 7200,
        hA_v, A1_v, B1_v, hB_v, A0_v, B0_v, 1);
    mp_round2_kernel<<<dim3(1000, 2), 320, 0, stream>>>(
        ioff_u, idlist_u, sef_u, Uw_u + 7200, Ub_u + 80, Mw_u + 6400, Mb_u + 80, nullptr,
        hB_u, A0_u, B0_u, hA_u, nullptr, nullptr,
        ioff_v, idlist_v, sef_v, Uw_v + 7200, Ub_v + 80, Mw_v + 6400, Mb_v + 80, nullptr,
        hB_v, A0_v, B0_v, hA_v, nullptr, nullptr, 0);

    // ---- set2set pair (collapsed; rT for coalesced gates1; R17-proven split) ----
    s2s_init2_kernel<<<dim3(1, 2), 64, 0, stream>>>(lsbih, lsbhh, lvbih, lvbhh, h1_u, c1_u, h1_v, c1_v);
    s2s_step0_kernel<<<dim3(125, 2), 256, 0, stream>>>(nodes_u, hA_u, h1_u, q_u, rT_u,
                                                       nodes_v, hA_v, h1_v, q_v, rT_v);
    s2s_base2_kernel<<<dim3(160, 2), 64, 0, stream>>>(lsWih, lsWhh, lsbih, lsbhh, h1_u,
                                                      lvWih, lvWhh, lvbih, lvbhh, h1_v, base2);
    s2s_gates1_kernel<<<dim3(625, 2), 256, 0, stream>>>(rT_u, lsWih, gT_u, rT_v, lvWih, gT_v, base2);
    s2s_upd1_kernel<<<dim3(125, 2), 256, 0, stream>>>(gT_u, nodes_u, hA_u, c1_u, q_u,
                                                      gT_v, nodes_v, hA_v, c1_v, q_v);

    // ---- bf16 casts + f32 qT (one launch) ----
    cast_all_kernel<<<dim3(5500, 2), 256, 0, stream>>>(q_u, q_v, guT, gvT, gub, gvb, qT_u, qT_v);

    // ---- fused interaction + after-features (y-split 4 + 4 blocks/CU occupancy) ----
    hipMemsetAsync(uafT, 0, 1280000 * sizeof(float), stream);   // uafT + vafT contiguous
    fused_kernel<<<dim3(125, 4, 2), 256, 0, stream>>>(gub, gvb, guT, gvT, inter, uafT, vafT);

    // ---- pools (step-0 collapsed; coalesced qT reads) ----
    pool_init2_kernel<<<dim3(1, 2), 256, 0, stream>>>(gsbih, gsbhh, gvbih, gvbhh,
                                                      ph_u, pc_u, pq_u, ph_v, pc_v, pq_v);
    pool_scores2_kernel<<<dim3(32, 2), 256, 0, stream>>>(uafT, qT_u, ph_u, sc_u, vafT, qT_v, ph_v, sc_v, pmax2);
    pool_r2_kernel<<<dim3(160, 2), 256, 0, stream>>>(uafT, qT_u, sc_u, vafT, qT_v, sc_v, pmax2, pq_u, pq_v);
    gates_pool2_kernel<<<dim3(640, 2), 64, 0, stream>>>(gsWih, gsWhh, gsbih, gsbhh, pq_u, ph_u,
                                                        gvWih, gvWhh, gvbih, gvbhh, pq_v, ph_v, pgts2);
    pool_point2_kernel<<<dim3(1, 2), 256, 0, stream>>>(pgts2, ph_u, pc_u, pq_u, ph_v, pc_v, pq_v);
    pool_scores2_kernel<<<dim3(32, 2), 256, 0, stream>>>(uafT, qT_u, ph_u, sc_u, vafT, qT_v, ph_v, sc_v, pmax2);
    pool_r2_kernel<<<dim3(160, 2), 256, 0, stream>>>(uafT, qT_u, sc_u, vafT, qT_v, sc_v, pmax2, pq_u, pq_v);

    // ---- final MLP ----
    gemv_kernel<<<360, 64, 0, stream>>>(w1, b1, pq_u, mx1, 640, 1);
    gemv_kernel<<<200, 64, 0, stream>>>(w2, b2, mx1, mx2, 360, 1);
    gemv_kernel<<<120, 64, 0, stream>>>(w3, b3, mx2, mx3, 200, 1);
    gemv_kernel<<<1, 64, 0, stream>>>(w4, b4, mx3, out, 120, 0);
}

// Round 20
// 634.982 us; speedup vs baseline: 1.3898x; 1.3898x over previous
//
#include <hip/hip_runtime.h>
#include <cstdint>
#include <cstddef>

#define NN 8000
#define NE 128000
#define NDv 40
#define EDv 10

typedef __attribute__((ext_vector_type(8))) short short8v;
typedef __attribute__((ext_vector_type(4))) float f32x4;

__device__ __forceinline__ float rcp_fast(float x) { return __builtin_amdgcn_rcpf(x); }
__device__ __forceinline__ float sigm(float x) { return rcp_fast(1.f + __expf(-x)); }
__device__ __forceinline__ float ftanh(float x) {
    float e = __expf(2.f * x);
    return 1.f - 2.f * rcp_fast(e + 1.f);
}
__device__ __forceinline__ short f2bf(float x) {   // RNE f32 -> bf16
    unsigned u = __builtin_bit_cast(unsigned, x);
    u += 0x7fffu + ((u >> 16) & 1u);
    return (short)(u >> 16);
}
__device__ __forceinline__ float wsum(float v) {
    for (int o = 32; o; o >>= 1) v += __shfl_down(v, o);
    return v;
}
__device__ __forceinline__ float wmax(float v) {
    for (int o = 32; o; o >>= 1) v = fmaxf(v, __shfl_down(v, o));
    return v;
}

// ---------------- CSR build (paired u/v via blockIdx.y) ----------------

__global__ __launch_bounds__(256) void csr_deg2_kernel(const int* __restrict__ ei_u, const int* __restrict__ ei_v,
                                                       int* __restrict__ deg_u, int* __restrict__ deg_v) {
    const int* ei = blockIdx.y ? ei_v : ei_u;
    int* deg = blockIdx.y ? deg_v : deg_u;
    int e = blockIdx.x * 256 + threadIdx.x;
    if (e < NE) atomicAdd(&deg[ei[e]], 1);
}

__global__ __launch_bounds__(256) void sef2_kernel(const int* __restrict__ ei_u, const int* __restrict__ ei_v,
                                                   const float* __restrict__ ef_u, const float* __restrict__ ef_v,
                                                   float* __restrict__ sef_u, float* __restrict__ sef_v) {
    const int* ei = blockIdx.y ? ei_v : ei_u;
    const float* ef = blockIdx.y ? ef_v : ef_u;
    float* sef = blockIdx.y ? sef_v : sef_u;
    int t = blockIdx.x * 256 + threadIdx.x;   // exactly NE*EDv
    int e = t / EDv, k = t % EDv;
    atomicAdd(&sef[ei[e] * EDv + k], ef[t]);
}

__global__ __launch_bounds__(64) void csr_scan2_kernel(const int* __restrict__ deg_u, const int* __restrict__ deg_v,
                                                       int* __restrict__ off_u, int* __restrict__ off_v,
                                                       int* __restrict__ woff_u, int* __restrict__ woff_v) {
    const int* deg = blockIdx.x ? deg_v : deg_u;
    int* off = blockIdx.x ? off_v : off_u;
    int* woff = blockIdx.x ? woff_v : woff_u;
    int l = threadIdx.x;
    int base = l * 125;
    int s = 0;
    for (int i = 0; i < 125; ++i) s += deg[base + i];
    int pre = s;
    for (int o = 1; o < 64; o <<= 1) { int t = __shfl_up(pre, o); if (l >= o) pre += t; }
    pre -= s;   // exclusive prefix
    int run = pre;
    for (int i = 0; i < 125; ++i) {
        off[base + i] = run; woff[base + i] = run;
        run += deg[base + i];
    }
    if (l == 63) off[NN] = run;
}

__global__ __launch_bounds__(256) void csr_fill2_kernel(const int* __restrict__ ei_u, const int* __restrict__ ei_v,
                                                        int* __restrict__ woff_u, int* __restrict__ woff_v,
                                                        int* __restrict__ dl_u, int* __restrict__ dl_v) {
    const int* ei = blockIdx.y ? ei_v : ei_u;
    int* woff = blockIdx.y ? woff_v : woff_u;
    int* dlist = blockIdx.y ? dl_v : dl_u;
    int e = blockIdx.x * 256 + threadIdx.x;
    if (e < NE) { int p = atomicAdd(&woff[ei[e]], 1); dlist[p] = ei[NE + e]; }
}

// ---------------- message passing ----------------

__global__ __launch_bounds__(256) void node_proj2_kernel(const float* __restrict__ h_u, const float* __restrict__ h_v,
                                                         const float* __restrict__ Uw_u, const float* __restrict__ Uw_v,
                                                         float* __restrict__ A_u, float* __restrict__ B_u,
                                                         float* __restrict__ A_v, float* __restrict__ B_v) {
    const float* h = blockIdx.y ? h_v : h_u;
    const float* Uw = blockIdx.y ? Uw_v : Uw_u;
    float* A = blockIdx.y ? A_v : A_u;
    float* B = blockIdx.y ? B_v : B_u;
    __shared__ float W[40][81];
    int tid = threadIdx.x;
    for (int s = tid; s < 3200; s += 256) W[s / 80][s % 80] = Uw[(s / 80) * 90 + (s % 80)];
    __syncthreads();
    int t = blockIdx.x * 256 + tid;   // exactly 8000*40
    int n = t / NDv, i = t % NDv;
    float hreg[40];
    const float* hr = h + n * NDv;
#pragma unroll
    for (int k4 = 0; k4 < 10; ++k4) {
        float4 v = *reinterpret_cast<const float4*>(hr + k4 * 4);
        hreg[k4 * 4 + 0] = v.x; hreg[k4 * 4 + 1] = v.y; hreg[k4 * 4 + 2] = v.z; hreg[k4 * 4 + 3] = v.w;
    }
    float a = 0.f, b = 0.f;
#pragma unroll
    for (int k = 0; k < NDv; ++k) { a += W[i][k] * hreg[k]; b += W[i][40 + k] * hreg[k]; }
    A[t] = a; B[t] = b;
}

// one full MP round: gather(msg in LDS) -> update(hout) -> proj for next round (A/B out).
// block = 320 threads = 8 nodes x 40 features; paired u/v via blockIdx.y.
__global__ __launch_bounds__(320) void mp_round2_kernel(
    const int* __restrict__ off_u, const int* __restrict__ dl_u, const float* __restrict__ sef_u,
    const float* __restrict__ UwE_u, const float* __restrict__ Ub_u,
    const float* __restrict__ Mw_u, const float* __restrict__ Mb_u, const float* __restrict__ UwN_u,
    const float* __restrict__ h_u, const float* __restrict__ A_u, const float* __restrict__ B_u,
    float* __restrict__ hout_u, float* __restrict__ Ao_u, float* __restrict__ Bo_u,
    const int* __restrict__ off_v, const int* __restrict__ dl_v, const float* __restrict__ sef_v,
    const float* __restrict__ UwE_v, const float* __restrict__ Ub_v,
    const float* __restrict__ Mw_v, const float* __restrict__ Mb_v, const float* __restrict__ UwN_v,
    const float* __restrict__ h_v, const float* __restrict__ A_v, const float* __restrict__ B_v,
    float* __restrict__ hout_v, float* __restrict__ Ao_v, float* __restrict__ Bo_v,
    int has_next) {
    const int* off = blockIdx.y ? off_v : off_u;
    const int* dlist = blockIdx.y ? dl_v : dl_u;
    const float* sef = blockIdx.y ? sef_v : sef_u;
    const float* UwE = blockIdx.y ? UwE_v : UwE_u;
    const float* Ub = blockIdx.y ? Ub_v : Ub_u;
    const float* Mw = blockIdx.y ? Mw_v : Mw_u;
    const float* Mb = blockIdx.y ? Mb_v : Mb_u;
    const float* UwN = blockIdx.y ? UwN_v : UwN_u;
    const float* h = blockIdx.y ? h_v : h_u;
    const float* A = blockIdx.y ? A_v : A_u;
    const float* B = blockIdx.y ? B_v : B_u;
    float* hout = blockIdx.y ? hout_v : hout_u;
    float* Ao = blockIdx.y ? Ao_v : Ao_u;
    float* Bo = blockIdx.y ? Bo_v : Bo_u;

    __shared__ float WM[40][81];
    __shared__ float WU[40][81];
    __shared__ float msgS[8][40];
    __shared__ float hS[8][41];
    __shared__ float houtS[8][41];

    int tid = threadIdx.x;
    for (int s = tid; s < 3200; s += 320) WM[s / 80][s % 80] = Mw[s];
    if (has_next)
        for (int s = tid; s < 3200; s += 320) WU[s / 80][s % 80] = UwN[(s / 80) * 90 + (s % 80)];
    int ln = tid / NDv, i = tid % NDv;
    int n = blockIdx.x * 8 + ln;
    int t = n * NDv + i;
    hS[ln][i] = h[t];

    const float* we = UwE + i * 90 + 80;
    const float* se = sef + n * EDv;
    int p0 = off[n], p1 = off[n + 1];
    float acc = (float)(p1 - p0) * (A[t] + Ub[i]);
#pragma unroll
    for (int k = 0; k < EDv; ++k) acc += we[k] * se[k];
    for (int p = p0; p < p1; ++p) acc += B[dlist[p] * NDv + i];
    msgS[ln][i] = acc;
    __syncthreads();

    float a2 = Mb[i];
#pragma unroll
    for (int k = 0; k < NDv; ++k) a2 += WM[i][k] * hS[ln][k];
#pragma unroll
    for (int k = 0; k < NDv; ++k) a2 += WM[i][40 + k] * msgS[ln][k];
    float ho = fmaxf(a2, 0.f);
    hout[t] = ho;
    if (has_next) {
        houtS[ln][i] = ho;
        __syncthreads();
        float a = 0.f, b = 0.f;
#pragma unroll
        for (int k = 0; k < NDv; ++k) { float hv = houtS[ln][k]; a += WU[i][k] * hv; b += WU[i][40 + k] * hv; }
        Ao[t] = a; Bo[t] = b;
    }
}

// ---------------- set2set pair (algebraically collapsed; zero initial state) ----------------

__global__ __launch_bounds__(64) void s2s_init2_kernel(const float* __restrict__ bih_u, const float* __restrict__ bhh_u,
                                                       const float* __restrict__ bih_v, const float* __restrict__ bhh_v,
                                                       float* __restrict__ h1_u, float* __restrict__ c1_u,
                                                       float* __restrict__ h1_v, float* __restrict__ c1_v) {
    const float* bih = blockIdx.y ? bih_v : bih_u;
    const float* bhh = blockIdx.y ? bhh_v : bhh_u;
    float* h1 = blockIdx.y ? h1_v : h1_u;
    float* c1 = blockIdx.y ? c1_v : c1_u;
    int i = threadIdx.x;
    if (i < 40) {
        float gi = bih[i] + bhh[i];
        float gg = bih[80 + i] + bhh[80 + i];
        float go = bih[120 + i] + bhh[120 + i];
        float c = sigm(gi) * ftanh(gg);
        c1[i] = c;
        h1[i] = sigm(go) * ftanh(c);
    }
}

// per-node step 0: e=dot(h0/ht, h1); 2-way softmax; q=[h1, r]; also rT[i][n] for coalesced gates1
__global__ __launch_bounds__(256) void s2s_step0_kernel(const float* __restrict__ h0_u, const float* __restrict__ ht_u,
                                                        const float* __restrict__ h1_u, float* __restrict__ q_u,
                                                        float* __restrict__ rT_u,
                                                        const float* __restrict__ h0_v, const float* __restrict__ ht_v,
                                                        const float* __restrict__ h1_v, float* __restrict__ q_v,
                                                        float* __restrict__ rT_v) {
    const float* h0 = blockIdx.y ? h0_v : h0_u;
    const float* ht = blockIdx.y ? ht_v : ht_u;
    const float* h1 = blockIdx.y ? h1_v : h1_u;
    float* q = blockIdx.y ? q_v : q_u;
    float* rT = blockIdx.y ? rT_v : rT_u;
    int tid = threadIdx.x;
    int nl = tid >> 2, lg = tid & 3;
    int n = blockIdx.x * 64 + nl;
    float h0r[10], htr[10];
    float e0 = 0.f, e1 = 0.f;
#pragma unroll
    for (int k = 0; k < 10; ++k) {
        int i = lg * 10 + k;
        h0r[k] = h0[n * 40 + i];
        htr[k] = ht[n * 40 + i];
        float hv = h1[i];
        e0 += h0r[k] * hv;
        e1 += htr[k] * hv;
    }
    e0 += __shfl_xor(e0, 1); e0 += __shfl_xor(e0, 2);
    e1 += __shfl_xor(e1, 1); e1 += __shfl_xor(e1, 2);
    float m = fmaxf(e0, e1);
    float p0 = __expf(e0 - m), p1 = __expf(e1 - m);
    float inv = rcp_fast(p0 + p1);
    float a0 = p0 * inv, a1 = p1 * inv;
#pragma unroll
    for (int k = 0; k < 10; ++k) {
        int i = lg * 10 + k;
        float r = a0 * h0r[k] + a1 * htr[k];
        q[n * 80 + i] = h1[i];
        q[n * 80 + 40 + i] = r;
        rT[i * NN + n] = r;
    }
}

__global__ __launch_bounds__(64) void s2s_base2_kernel(const float* __restrict__ Wih_u, const float* __restrict__ Whh_u,
                                                       const float* __restrict__ bih_u, const float* __restrict__ bhh_u,
                                                       const float* __restrict__ h1_u,
                                                       const float* __restrict__ Wih_v, const float* __restrict__ Whh_v,
                                                       const float* __restrict__ bih_v, const float* __restrict__ bhh_v,
                                                       const float* __restrict__ h1_v,
                                                       float* __restrict__ base2) {
    const float* Wih = blockIdx.y ? Wih_v : Wih_u;
    const float* Whh = blockIdx.y ? Whh_v : Whh_u;
    const float* bih = blockIdx.y ? bih_v : bih_u;
    const float* bhh = blockIdx.y ? bhh_v : bhh_u;
    const float* h1 = blockIdx.y ? h1_v : h1_u;
    int j = blockIdx.x;
    int lane = threadIdx.x;
    float p = 0.f;
    if (lane < 40) p = (Wih[j * 80 + lane] + Whh[j * 40 + lane]) * h1[lane];
    p = wsum(p);
    if (lane == 0) base2[blockIdx.y * 160 + j] = p + bih[j] + bhh[j];
}

// step-1 gates: gT[j][n] = base[j] + Wih[j,40:80]·r[n]; r read coalesced from rT
__global__ __launch_bounds__(256) void s2s_gates1_kernel(const float* __restrict__ rT_u, const float* __restrict__ Wih_u,
                                                         float* __restrict__ gT_u,
                                                         const float* __restrict__ rT_v, const float* __restrict__ Wih_v,
                                                         float* __restrict__ gT_v,
                                                         const float* __restrict__ base2) {
    const float* rT = blockIdx.y ? rT_v : rT_u;
    const float* Wih = blockIdx.y ? Wih_v : Wih_u;
    float* gatesT = blockIdx.y ? gT_v : gT_u;
    const float* base = base2 + blockIdx.y * 160;
    int t = blockIdx.x * 256 + threadIdx.x;   // exactly 8000*20
    int n = t % NN;
    int jg = t / NN;
    float rr[40];
#pragma unroll
    for (int k = 0; k < 40; ++k) rr[k] = rT[k * NN + n];
#pragma unroll
    for (int jj = 0; jj < 8; ++jj) {
        int j = jg * 8 + jj;
        const float* wi = Wih + j * 80 + 40;
        float acc = base[j];
#pragma unroll
        for (int k = 0; k < 40; ++k) acc += wi[k] * rr[k];
        gatesT[j * NN + n] = acc;
    }
}

__global__ __launch_bounds__(256) void s2s_upd1_kernel(const float* __restrict__ gT_u, const float* __restrict__ h0_u,
                                                       const float* __restrict__ ht_u, const float* __restrict__ c1_u,
                                                       float* __restrict__ q_u,
                                                       const float* __restrict__ gT_v, const float* __restrict__ h0_v,
                                                       const float* __restrict__ ht_v, const float* __restrict__ c1_v,
                                                       float* __restrict__ q_v) {
    const float* gT = blockIdx.y ? gT_v : gT_u;
    const float* h0 = blockIdx.y ? h0_v : h0_u;
    const float* ht = blockIdx.y ? ht_v : ht_u;
    const float* c1 = blockIdx.y ? c1_v : c1_u;
    float* q = blockIdx.y ? q_v : q_u;
    int tid = threadIdx.x;
    int nl = tid >> 2, lg = tid & 3;
    int n = blockIdx.x * 64 + nl;
    float h0r[10], htr[10], hnr[10];
    float e0 = 0.f, e1 = 0.f;
#pragma unroll
    for (int k = 0; k < 10; ++k) {
        int i = lg * 10 + k;
        float gi = gT[i * NN + n];
        float gf = gT[(40 + i) * NN + n];
        float gg = gT[(80 + i) * NN + n];
        float go = gT[(120 + i) * NN + n];
        float cn = sigm(gf) * c1[i] + sigm(gi) * ftanh(gg);
        float hn = sigm(go) * ftanh(cn);
        hnr[k] = hn;
        h0r[k] = h0[n * 40 + i];
        htr[k] = ht[n * 40 + i];
        e0 += h0r[k] * hn;
        e1 += htr[k] * hn;
    }
    e0 += __shfl_xor(e0, 1); e0 += __shfl_xor(e0, 2);
    e1 += __shfl_xor(e1, 1); e1 += __shfl_xor(e1, 2);
    float m = fmaxf(e0, e1);
    float p0 = __expf(e0 - m), p1 = __expf(e1 - m);
    float inv = rcp_fast(p0 + p1);
    float a0 = p0 * inv, a1 = p1 * inv;
#pragma unroll
    for (int k = 0; k < 10; ++k) {
        int i = lg * 10 + k;
        q[n * 80 + i] = hnr[k];
        q[n * 80 + 40 + i] = a0 * h0r[k] + a1 * htr[k];
    }
}

// ---------------- bf16 casts + f32 transposed copy (u/v via blockIdx.y) ----------------

__global__ __launch_bounds__(256) void cast_all_kernel(const float* __restrict__ gu, const float* __restrict__ gv,
                                                       short* __restrict__ ouT, short* __restrict__ ovT,
                                                       short* __restrict__ oub, short* __restrict__ ovb,
                                                       float* __restrict__ qTu, float* __restrict__ qTv) {
    const float* g = blockIdx.y ? gv : gu;
    if (blockIdx.x < 2500) {   // transposed [80][8000]: bf16 + f32 copies
        short* o = blockIdx.y ? ovT : ouT;
        float* qT = blockIdx.y ? qTv : qTu;
        int t = blockIdx.x * 256 + threadIdx.x;
        int m = t % NN, f = t / NN;
        float val = g[m * 80 + f];
        o[t] = f2bf(val);
        qT[t] = val;
    } else {                    // padded row-major [8000][96]
        short* o = blockIdx.y ? ovb : oub;
        int t = (blockIdx.x - 2500) * 256 + threadIdx.x;
        int m = t / 96, k = t % 96;
        o[t] = (k < 80) ? f2bf(g[m * 80 + k]) : (short)0;
    }
}

// ---------------- fused interaction + after-feature (barrier-free, SW-pipelined; y-split 2) ----------------

__global__ __launch_bounds__(256, 2) void fused_kernel(const short* __restrict__ gub, const short* __restrict__ gvb,
                                                       const short* __restrict__ guT, const short* __restrict__ gvT,
                                                       float* __restrict__ inter,
                                                       float* __restrict__ uafT, float* __restrict__ vafT) {
    __shared__ short P[4][16][72];   // per-wave [row][col], 144B row stride
    const short* Xb; const short* Yb; const short* YT; float* afT;
    bool storeI = (blockIdx.z == 0);
    if (storeI) { Xb = gub; Yb = gvb; YT = gvT; afT = uafT; }
    else        { Xb = gvb; Yb = gub; YT = guT; afT = vafT; }
    int tid = threadIdx.x;
    int w = tid >> 6, l = tid & 63;
    int lrow = l & 15, lk = l >> 4;
    int x0 = blockIdx.x * 64;
    int it0 = (125 * blockIdx.y) >> 1;
    int it1 = (125 * (blockIdx.y + 1)) >> 1;
    short8v a_x[3];
    const short* arow = Xb + (size_t)(x0 + w * 16 + lrow) * 96 + lk * 8;
#pragma unroll
    for (int ks = 0; ks < 3; ++ks) a_x[ks] = *reinterpret_cast<const short8v*>(arow + ks * 32);
    const short* ybase = Yb + (size_t)lrow * 96 + lk * 8;

    f32x4 acc[5] = {};
    short8v bc[12], bn[12];
#pragma unroll
    for (int i = 0; i < 12; ++i) {
        int ks = i >> 2, nt = i & 3;
        bc[i] = *reinterpret_cast<const short8v*>(ybase + (size_t)(it0 * 64 + nt * 16) * 96 + ks * 32);
    }
    for (int it = it0; it < it1; ++it) {
        int k0 = it * 64;
        if (it + 1 < it1) {
#pragma unroll
            for (int i = 0; i < 12; ++i) {
                int ks = i >> 2, nt = i & 3;
                bn[i] = *reinterpret_cast<const short8v*>(ybase + (size_t)(k0 + 64 + nt * 16) * 96 + ks * 32);
            }
        }
        short8v byt[10];
#pragma unroll
        for (int ks2 = 0; ks2 < 2; ++ks2)
#pragma unroll
            for (int ft = 0; ft < 5; ++ft)
                byt[ks2 * 5 + ft] = *reinterpret_cast<const short8v*>(YT + (size_t)(ft * 16 + lrow) * NN + k0 + ks2 * 32 + lk * 8);
        f32x4 accI[4] = {};
#pragma unroll
        for (int ks = 0; ks < 3; ++ks)
#pragma unroll
            for (int nt = 0; nt < 4; ++nt)
                accI[nt] = __builtin_amdgcn_mfma_f32_16x16x32_bf16(a_x[ks], bc[ks * 4 + nt], accI[nt], 0, 0, 0);
#pragma unroll
        for (int nt = 0; nt < 4; ++nt)
#pragma unroll
            for (int r = 0; r < 4; ++r)
                P[w][lk * 4 + r][nt * 16 + lrow] = f2bf(ftanh(accI[nt][r]));
        // wave-private LDS: same-wave write->read is in-order, no barrier needed
#pragma unroll
        for (int ks2 = 0; ks2 < 2; ++ks2) {
            short8v ap = *reinterpret_cast<const short8v*>(&P[w][lrow][ks2 * 32 + lk * 8]);
#pragma unroll
            for (int ft = 0; ft < 5; ++ft)
                acc[ft] = __builtin_amdgcn_mfma_f32_16x16x32_bf16(ap, byt[ks2 * 5 + ft], acc[ft], 0, 0, 0);
        }
        if (storeI) {
#pragma unroll
            for (int nt = 0; nt < 4; ++nt)
#pragma unroll
                for (int r = 0; r < 4; ++r)
                    inter[(size_t)(x0 + w * 16 + lk * 4 + r) * NN + (k0 + nt * 16 + lrow)] = accI[nt][r];
        }
#pragma unroll
        for (int i = 0; i < 12; ++i) bc[i] = bn[i];
    }
    int xout = x0 + w * 16 + lk * 4;
#pragma unroll
    for (int ft = 0; ft < 5; ++ft)
#pragma unroll
        for (int r = 0; r < 4; ++r)
            atomicAdd(&afT[(size_t)(ft * 16 + lrow) * NN + xout + r], acc[ft][r]);
}

// ---------------- set2set pool (batch 1, h_d=160; paired u/v; step-0 collapsed) ----------------

__global__ __launch_bounds__(256) void pool_init2_kernel(const float* __restrict__ bih_u, const float* __restrict__ bhh_u,
                                                         const float* __restrict__ bih_v, const float* __restrict__ bhh_v,
                                                         float* __restrict__ ph_u, float* __restrict__ pc_u,
                                                         float* __restrict__ pq_u,
                                                         float* __restrict__ ph_v, float* __restrict__ pc_v,
                                                         float* __restrict__ pq_v) {
    const float* bih = blockIdx.y ? bih_v : bih_u;
    const float* bhh = blockIdx.y ? bhh_v : bhh_u;
    float* ph = blockIdx.y ? ph_v : ph_u;
    float* pc = blockIdx.y ? pc_v : pc_u;
    float* pq = blockIdx.y ? pq_v : pq_u;
    int i = threadIdx.x;
    if (i < 160) {
        float gi = bih[i] + bhh[i];
        float gg = bih[320 + i] + bhh[320 + i];
        float go = bih[480 + i] + bhh[480 + i];
        float c = sigm(gi) * ftanh(gg);
        pc[i] = c;
        float h = sigm(go) * ftanh(c);
        ph[i] = h;
        pq[i] = h;
    }
}

__global__ __launch_bounds__(64) void gates_pool2_kernel(const float* __restrict__ Wih_u, const float* __restrict__ Whh_u,
                                                         const float* __restrict__ bih_u, const float* __restrict__ bhh_u,
                                                         const float* __restrict__ q_u, const float* __restrict__ h_u,
                                                         const float* __restrict__ Wih_v, const float* __restrict__ Whh_v,
                                                         const float* __restrict__ bih_v, const float* __restrict__ bhh_v,
                                                         const float* __restrict__ q_v, const float* __restrict__ h_v,
                                                         float* __restrict__ gts2) {
    const float* Wih = blockIdx.y ? Wih_v : Wih_u;
    const float* Whh = blockIdx.y ? Whh_v : Whh_u;
    const float* bih = blockIdx.y ? bih_v : bih_u;
    const float* bhh = blockIdx.y ? bhh_v : bhh_u;
    const float* q = blockIdx.y ? q_v : q_u;
    const float* h = blockIdx.y ? h_v : h_u;
    float* gts = gts2 + blockIdx.y * 640;
    int j = blockIdx.x;
    int lane = threadIdx.x;
    const float* wi = Wih + j * 320;
    const float* wh = Whh + j * 160;
    float p = 0.f;
#pragma unroll
    for (int k4 = 0; k4 < 5; ++k4) { int k = lane + k4 * 64; p += wi[k] * q[k]; }
#pragma unroll
    for (int k4 = 0; k4 < 3; ++k4) { int k = lane + k4 * 64; if (k < 160) p += wh[k] * h[k]; }
    p = wsum(p);
    if (lane == 0) gts[j] = p + bih[j] + bhh[j];
}

__global__ __launch_bounds__(256) void pool_point2_kernel(const float* __restrict__ gts2,
                                                          float* __restrict__ h_u, float* __restrict__ c_u,
                                                          float* __restrict__ q_u,
                                                          float* __restrict__ h_v, float* __restrict__ c_v,
                                                          float* __restrict__ q_v) {
    const float* gts = gts2 + blockIdx.y * 640;
    float* h = blockIdx.y ? h_v : h_u;
    float* c = blockIdx.y ? c_v : c_u;
    float* q = blockIdx.y ? q_v : q_u;
    int tid = threadIdx.x;
    if (tid < 160) {
        float cn = sigm(gts[160 + tid]) * c[tid] + sigm(gts[tid]) * ftanh(gts[320 + tid]);
        c[tid] = cn;
        float hn = sigm(gts[480 + tid]) * ftanh(cn);
        h[tid] = hn;
        q[tid] = hn;   // q_star[0:160] = h
    }
}

__global__ __launch_bounds__(256) void pool_scores2_kernel(const float* __restrict__ uafT, const float* __restrict__ qTu,
                                                           const float* __restrict__ h_u, float* __restrict__ sc_u,
                                                           const float* __restrict__ vafT, const float* __restrict__ qTv,
                                                           const float* __restrict__ h_v, float* __restrict__ sc_v,
                                                           float* __restrict__ pmax2) {
    const float* afT = blockIdx.y ? vafT : uafT;
    const float* qT = blockIdx.y ? qTv : qTu;
    const float* h = blockIdx.y ? h_v : h_u;
    float* scores = blockIdx.y ? sc_v : sc_u;
    float* pmax = pmax2 + blockIdx.y * 32;
    int tid = threadIdx.x;
    int n = blockIdx.x * 256 + tid;
    float s = -3.4e38f;
    if (n < NN) {
        float acc = 0.f;
#pragma unroll 8
        for (int k = 0; k < 80; ++k) acc += afT[k * NN + n] * h[k];
#pragma unroll 8
        for (int k = 0; k < 80; ++k) acc += qT[k * NN + n] * h[80 + k];
        scores[n] = acc;
        s = acc;
    }
    __shared__ float red[4];
    float m = wmax(s);
    if ((tid & 63) == 0) red[tid >> 6] = m;
    __syncthreads();
    if (tid == 0) pmax[blockIdx.x] = fmaxf(fmaxf(red[0], red[1]), fmaxf(red[2], red[3]));
}

__global__ __launch_bounds__(256) void pool_r2_kernel(const float* __restrict__ uafT, const float* __restrict__ qTu,
                                                      const float* __restrict__ sc_u,
                                                      const float* __restrict__ vafT, const float* __restrict__ qTv,
                                                      const float* __restrict__ sc_v,
                                                      const float* __restrict__ pmax2,
                                                      float* __restrict__ pq_u, float* __restrict__ pq_v) {
    const float* afT = blockIdx.y ? vafT : uafT;
    const float* qT = blockIdx.y ? qTv : qTu;
    const float* scores = blockIdx.y ? sc_v : sc_u;
    float* q = blockIdx.y ? pq_v : pq_u;
    const float* pmax = pmax2 + blockIdx.y * 32;
    int f = blockIdx.x;   // 0..159
    int tid = threadIdx.x;
    __shared__ float smax;
    __shared__ float reda[4], redd[4];
    if (tid < 64) {
        float m = (tid < 32) ? pmax[tid] : -3.4e38f;
        m = wmax(m);
        if (tid == 0) smax = m;
    }
    __syncthreads();
    float m = smax;
    const float* x = (f < 80) ? (afT + (size_t)f * NN) : (qT + (size_t)(f - 80) * NN);
    float acc = 0.f, den = 0.f;
    for (int n = tid; n < NN; n += 256) { float e = __expf(scores[n] - m); den += e; acc += e * x[n]; }
    float wa = wsum(acc), wd = wsum(den);
    if ((tid & 63) == 0) { reda[tid >> 6] = wa; redd[tid >> 6] = wd; }
    __syncthreads();
    if (tid == 0) {
        float A = reda[0] + reda[1] + reda[2] + reda[3];
        float D = redd[0] + redd[1] + redd[2] + redd[3];
        q[160 + f] = A * rcp_fast(D);
    }
}

// ---------------- final MLP ----------------

__global__ __launch_bounds__(64) void gemv_kernel(const float* __restrict__ W, const float* __restrict__ b,
                                                  const float* __restrict__ x, float* __restrict__ y,
                                                  int K, int relu) {
    int j = blockIdx.x;
    int lane = threadIdx.x;
    const float* w = W + (size_t)j * K;
    float p = 0.f;
    for (int k = lane; k < K; k += 64) p += w[k] * x[k];
    p = wsum(p);
    if (lane == 0) {
        p += b[j];
        y[j] = relu ? fmaxf(p, 0.f) : p;
    }
}

// ---------------- launch ----------------

extern "C" void kernel_launch(void* const* d_in, const int* in_sizes, int n_in,
                              void* d_out, int out_size, void* d_ws, size_t ws_size,
                              hipStream_t stream) {
    const float* nodes_u = (const float*)d_in[0];
    const int* ei_u = (const int*)d_in[1];
    const float* ef_u = (const float*)d_in[2];
    const float* nodes_v = (const float*)d_in[3];
    const int* ei_v = (const int*)d_in[4];
    const float* ef_v = (const float*)d_in[5];
    const float* Uw_u = (const float*)d_in[6];
    const float* Ub_u = (const float*)d_in[7];
    const float* Mw_u = (const float*)d_in[8];
    const float* Mb_u = (const float*)d_in[9];
    const float* Uw_v = (const float*)d_in[10];
    const float* Ub_v = (const float*)d_in[11];
    const float* Mw_v = (const float*)d_in[12];
    const float* Mb_v = (const float*)d_in[13];
    const float* lsWih = (const float*)d_in[14];
    const float* lsWhh = (const float*)d_in[15];
    const float* lsbih = (const float*)d_in[16];
    const float* lsbhh = (const float*)d_in[17];
    const float* lvWih = (const float*)d_in[18];
    const float* lvWhh = (const float*)d_in[19];
    const float* lvbih = (const float*)d_in[20];
    const float* lvbhh = (const float*)d_in[21];
    const float* gsWih = (const float*)d_in[22];
    const float* gsWhh = (const float*)d_in[23];
    const float* gsbih = (const float*)d_in[24];
    const float* gsbhh = (const float*)d_in[25];
    const float* gvWih = (const float*)d_in[26];
    const float* gvWhh = (const float*)d_in[27];
    const float* gvbih = (const float*)d_in[28];
    const float* gvbhh = (const float*)d_in[29];
    const float* w1 = (const float*)d_in[30];
    const float* b1 = (const float*)d_in[31];
    const float* w2 = (const float*)d_in[32];
    const float* b2 = (const float*)d_in[33];
    const float* w3 = (const float*)d_in[34];
    const float* b3 = (const float*)d_in[35];
    const float* w4 = (const float*)d_in[36];
    const float* b4 = (const float*)d_in[37];

    float* ws = (float*)d_ws;
    float* hA_u = ws + 0;
    float* hB_u = ws + 320000;
    float* hA_v = ws + 640000;
    float* hB_v = ws + 960000;
    float* A0_u = ws + 1600000;
    float* B0_u = ws + 1920000;
    float* q_u  = ws + 2240000;   // gu [8000,80]; during MP: A1_u/B1_u ping-pong
    float* q_v  = ws + 2880000;   // gv [8000,80]; during MP: A1_v/B1_v
    float* A1_u = ws + 2240000;
    float* B1_u = ws + 2560000;
    float* A1_v = ws + 2880000;
    float* B1_v = ws + 3200000;
    float* sef_u = ws + 4160000;  // [8000][10] — MP phase
    float* sef_v = ws + 4240000;  // [8000][10]
    float* gT_u = ws + 4160000;   // [160][8000] — s2s phase (sef dead after MP)
    float* gT_v = ws + 5440000;   // [160][8000] — overlaps uafT/vafT (memset later)
    float* uafT = ws + 5440000;   // [80][8000] — fused phase (gT_v dead)
    float* vafT = ws + 6080000;   // [80][8000]
    float* rT_u = ws + 1600000;   // [40][8000] — s2s phase (A0_u dead); overwritten by qT_u in cast
    float* rT_v = ws + 1920000;   // [40][8000] (B0_u region)
    float* qT_u = ws + 1600000;   // [80][8000] f32 — cast phase
    float* qT_v = ws + 2240000;   // [80][8000] f32 — q_u region dead after cast
    float* sc_u = ws + 6720000;   // [8000]
    float* sc_v = ws + 6728000;   // [8000]
    float* pmax2 = ws + 6736000;  // [2][32]
    float* pq_u = ws + 6736080;   // [320]  (pq_u|pq_v contiguous = MLP input)
    float* pq_v = ws + 6736400;   // [320]
    float* ph_u = ws + 6736720;   // [160]
    float* pc_u = ws + 6736880;   // [160]
    float* ph_v = ws + 6737040;   // [160]
    float* pc_v = ws + 6737200;   // [160]
    float* pgts2 = ws + 6737360;  // [2][640]
    float* mx1  = ws + 6738640;   // 360
    float* mx2  = ws + 6739000;   // 200
    float* mx3  = ws + 6739200;   // 120
    float* h1_u = ws + 6739320;   // [40]
    float* c1_u = ws + 6739360;   // [40]
    float* h1_v = ws + 6739400;   // [40]
    float* c1_v = ws + 6739440;   // [40]
    float* base2 = ws + 6739480;  // [2][160] -> ends 6739800
    int* ioff_u   = (int*)(ws + 6740000);   // 8064
    int* idlist_u = (int*)(ws + 6748064);   // 128000
    int* ioff_v   = (int*)(ws + 6876064);   // 8064
    int* idlist_v = (int*)(ws + 6884128);   // 128000
    int* iwoff_u  = (int*)(ws + 7012128);   // 8064 (CSR phase only)
    int* ideg_u   = (int*)(ws + 7020192);   // 8064
    int* iwoff_v  = (int*)(ws + 7028256);   // 8064
    int* ideg_v   = (int*)(ws + 7036320);   // 8064 -> ends 7044384
    // MP phase: v proj set 0 (CSR scratch above dead by MP)
    float* A0_v = ws + 7339536;   // [320000]
    float* B0_v = ws + 7659536;   // [320000] -> ends 7979536

    // bf16 buffers reuse the (dead by then) message-passing region
    short* guT = (short*)(ws + 0);        // [80][8000]
    short* gvT = (short*)(ws + 320000);   // [80][8000]
    short* gub = (short*)(ws + 640000);   // [8000][96]
    short* gvb = (short*)(ws + 1024000);  // [8000][96]

    float* out = (float*)d_out;
    float* inter = out + 1;

    // ---- CSR + edge-feature sums (paired) ----
    hipMemsetAsync(ideg_u, 0, (7044384 - 7020192) * sizeof(int), stream);  // ideg_u, iwoff_v, ideg_v
    hipMemsetAsync(sef_u, 0, 2 * NN * EDv * sizeof(float), stream);        // sef_u + sef_v
    csr_deg2_kernel<<<dim3(500, 2), 256, 0, stream>>>(ei_u, ei_v, ideg_u, ideg_v);
    csr_scan2_kernel<<<2, 64, 0, stream>>>(ideg_u, ideg_v, ioff_u, ioff_v, iwoff_u, iwoff_v);
    csr_fill2_kernel<<<dim3(500, 2), 256, 0, stream>>>(ei_u, ei_v, iwoff_u, iwoff_v, idlist_u, idlist_v);
    sef2_kernel<<<dim3(5000, 2), 256, 0, stream>>>(ei_u, ei_v, ef_u, ef_v, sef_u, sef_v);

    // ---- message passing: proj0 + 3 fused rounds (8 nodes/block) ----
    node_proj2_kernel<<<dim3(1250, 2), 256, 0, stream>>>(nodes_u, nodes_v, Uw_u, Uw_v, A0_u, B0_u, A0_v, B0_v);
    mp_round2_kernel<<<dim3(1000, 2), 320, 0, stream>>>(
        ioff_u, idlist_u, sef_u, Uw_u, Ub_u, Mw_u, Mb_u, Uw_u + 3600,
        nodes_u, A0_u, B0_u, hA_u, A1_u, B1_u,
        ioff_v, idlist_v, sef_v, Uw_v, Ub_v, Mw_v, Mb_v, Uw_v + 3600,
        nodes_v, A0_v, B0_v, hA_v, A1_v, B1_v, 1);
    mp_round2_kernel<<<dim3(1000, 2), 320, 0, stream>>>(
        ioff_u, idlist_u, sef_u, Uw_u + 3600, Ub_u + 40, Mw_u + 3200, Mb_u + 40, Uw_u + 7200,
        hA_u, A1_u, B1_u, hB_u, A0_u, B0_u,
        ioff_v, idlist_v, sef_v, Uw_v + 3600, Ub_v + 40, Mw_v + 3200, Mb_v + 40, Uw_v + 7200,
        hA_v, A1_v, B1_v, hB_v, A0_v, B0_v, 1);
    mp_round2_kernel<<<dim3(1000, 2), 320, 0, stream>>>(
        ioff_u, idlist_u, sef_u, Uw_u + 7200, Ub_u + 80, Mw_u + 6400, Mb_u + 80, nullptr,
        hB_u, A0_u, B0_u, hA_u, nullptr, nullptr,
        ioff_v, idlist_v, sef_v, Uw_v + 7200, Ub_v + 80, Mw_v + 6400, Mb_v + 80, nullptr,
        hB_v, A0_v, B0_v, hA_v, nullptr, nullptr, 0);

    // ---- set2set pair (collapsed; rT for coalesced gates1) ----
    s2s_init2_kernel<<<dim3(1, 2), 64, 0, stream>>>(lsbih, lsbhh, lvbih, lvbhh, h1_u, c1_u, h1_v, c1_v);
    s2s_step0_kernel<<<dim3(125, 2), 256, 0, stream>>>(nodes_u, hA_u, h1_u, q_u, rT_u,
                                                       nodes_v, hA_v, h1_v, q_v, rT_v);
    s2s_base2_kernel<<<dim3(160, 2), 64, 0, stream>>>(lsWih, lsWhh, lsbih, lsbhh, h1_u,
                                                      lvWih, lvWhh, lvbih, lvbhh, h1_v, base2);
    s2s_gates1_kernel<<<dim3(625, 2), 256, 0, stream>>>(rT_u, lsWih, gT_u, rT_v, lvWih, gT_v, base2);
    s2s_upd1_kernel<<<dim3(125, 2), 256, 0, stream>>>(gT_u, nodes_u, hA_u, c1_u, q_u,
                                                      gT_v, nodes_v, hA_v, c1_v, q_v);

    // ---- bf16 casts + f32 qT (one launch) ----
    cast_all_kernel<<<dim3(5500, 2), 256, 0, stream>>>(q_u, q_v, guT, gvT, gub, gvb, qT_u, qT_v);

    // ---- fused interaction + after-features (y-split 2; best-known config) ----
    hipMemsetAsync(uafT, 0, 1280000 * sizeof(float), stream);   // uafT + vafT contiguous
    fused_kernel<<<dim3(125, 2, 2), 256, 0, stream>>>(gub, gvb, guT, gvT, inter, uafT, vafT);

    // ---- pools (step-0 collapsed; coalesced qT reads) ----
    pool_init2_kernel<<<dim3(1, 2), 256, 0, stream>>>(gsbih, gsbhh, gvbih, gvbhh,
                                                      ph_u, pc_u, pq_u, ph_v, pc_v, pq_v);
    pool_scores2_kernel<<<dim3(32, 2), 256, 0, stream>>>(uafT, qT_u, ph_u, sc_u, vafT, qT_v, ph_v, sc_v, pmax2);
    pool_r2_kernel<<<dim3(160, 2), 256, 0, stream>>>(uafT, qT_u, sc_u, vafT, qT_v, sc_v, pmax2, pq_u, pq_v);
    gates_pool2_kernel<<<dim3(640, 2), 64, 0, stream>>>(gsWih, gsWhh, gsbih, gsbhh, pq_u, ph_u,
                                                        gvWih, gvWhh, gvbih, gvbhh, pq_v, ph_v, pgts2);
    pool_point2_kernel<<<dim3(1, 2), 256, 0, stream>>>(pgts2, ph_u, pc_u, pq_u, ph_v, pc_v, pq_v);
    pool_scores2_kernel<<<dim3(32, 2), 256, 0, stream>>>(uafT, qT_u, ph_u, sc_u, vafT, qT_v, ph_v, sc_v, pmax2);
    pool_r2_kernel<<<dim3(160, 2), 256, 0, stream>>>(uafT, qT_u, sc_u, vafT, qT_v, sc_v, pmax2, pq_u, pq_v);

    // ---- final MLP ----
    gemv_kernel<<<360, 64, 0, stream>>>(w1, b1, pq_u, mx1, 640, 1);
    gemv_kernel<<<200, 64, 0, stream>>>(w2, b2, mx1, mx2, 360, 1);
    gemv_kernel<<<120, 64, 0, stream>>>(w3, b3, mx2, mx3, 200, 1);
    gemv_kernel<<<1, 64, 0, stream>>>(w4, b4, mx3, out, 120, 0);
}